// Round 7
// baseline (1582.848 us; speedup 1.0000x reference)
//
#include <hip/hip_runtime.h>

#define B_ 16
#define C_ 64
#define H_ 128
#define W_ 256
#define K_ 9
#define KDIM_ (K_*C_)            // 576

typedef __attribute__((ext_vector_type(8))) short short8_t;
typedef __attribute__((ext_vector_type(4))) float f32x4;

static __device__ __forceinline__ float bf2f(unsigned short u) {
  union { unsigned int i; float f; } v; v.i = ((unsigned int)u) << 16; return v.f;
}
static __device__ __forceinline__ unsigned short f2bf(float f) {
  union { float f; unsigned int i; } v; v.f = f;
  unsigned int r = v.i + 0x7FFF + ((v.i >> 16) & 1);   // RNE
  return (unsigned short)(r >> 16);
}

// async global->LDS, 16B per lane; lds base wave-uniform, lanes fill +lane*16
static __device__ __forceinline__ void gload_lds16(const void* g, void* l) {
  __builtin_amdgcn_global_load_lds(
      (const __attribute__((address_space(1))) unsigned int*)g,
      (__attribute__((address_space(3))) unsigned int*)l, 16, 0, 0);
}

// All 4 weight tensors [co][ci][kk] fp32 -> A2 chunk layout (16B chunk = 8
// consecutive k for one co): A2[(c*64+co)*8 + (k&7)], c = k>>3, k = kk*64+ci.
__global__ __launch_bounds__(256) void prep_w_all(const float* __restrict__ w0,
                                                  const float* __restrict__ w1,
                                                  const float* __restrict__ w2,
                                                  const float* __restrict__ w3,
                                                  unsigned short* __restrict__ A2) {
  int idx = blockIdx.x * 256 + threadIdx.x;
  if (idx >= C_ * KDIM_) return;
  int which = blockIdx.y;
  const float* w = (which == 0) ? w0 : (which == 1) ? w1 : (which == 2) ? w2 : w3;
  unsigned short* out = A2 + (size_t)which * (C_ * KDIM_);
  int co = idx / KDIM_, k = idx % KDIM_;
  int ci = k & 63, kk = k >> 6;
  out[((size_t)(k >> 3) * 64 + co) * 8 + (k & 7)] =
      f2bf(w[((size_t)co * C_ + ci) * K_ + kk]);
}

// fp32 NCHW -> bf16 ci-minor [b][h][w][ci]
__global__ __launch_bounds__(256) void transpose_in(const float* __restrict__ x,
                                                    unsigned short* __restrict__ Xt) {
  __shared__ float tile[64][65];
  const int w0 = blockIdx.x * 64, h = blockIdx.y, b = blockIdx.z;
  const int t = threadIdx.x;
#pragma unroll
  for (int rep = 0; rep < 16; ++rep) {
    int idx = rep * 256 + t;
    int ci = idx >> 6, wl = idx & 63;
    tile[ci][wl] = x[((size_t)(b * C_ + ci) * H_ + h) * W_ + w0 + wl];
  }
  __syncthreads();
#pragma unroll
  for (int rep = 0; rep < 8; ++rep) {
    int idx = rep * 256 + t;
    int wl = idx >> 5, cp = idx & 31;
    unsigned v = (unsigned)f2bf(tile[cp*2][wl]) | ((unsigned)f2bf(tile[cp*2+1][wl]) << 16);
    *(unsigned*)(Xt + ((size_t)(b * H_ + h) * W_ + w0 + wl) * C_ + cp * 2) = v;
  }
}

// bf16 ci-minor -> fp32 NCHW (final output)
__global__ __launch_bounds__(256) void transpose_out(const unsigned short* __restrict__ F,
                                                     float* __restrict__ out) {
  __shared__ float tile[64][65];
  const int w0 = blockIdx.x * 64, h = blockIdx.y, b = blockIdx.z;
  const int t = threadIdx.x;
#pragma unroll
  for (int rep = 0; rep < 8; ++rep) {
    int idx = rep * 256 + t;
    int wl = idx >> 5, cp = idx & 31;
    unsigned v = *(const unsigned*)(F + ((size_t)(b * H_ + h) * W_ + w0 + wl) * C_ + cp * 2);
    tile[cp*2][wl]   = bf2f((unsigned short)v);
    tile[cp*2+1][wl] = bf2f((unsigned short)(v >> 16));
  }
  __syncthreads();
#pragma unroll
  for (int rep = 0; rep < 16; ++rep) {
    int idx = rep * 256 + t;
    int ci = idx >> 6, wl = idx & 63;
    out[((size_t)(b * C_ + ci) * H_ + h) * W_ + w0 + wl] = tile[ci][wl];
  }
}

// ===== MFMA conv, 4 blocks/CU =====
// Window = 136 staged-axis positions x 64 ci (17.4KB), double-buffered.
// MODE 0 (conv along W): block = (half,hgroup,b); iterates 4 rows h; window =
//   w in [half*128-4, half*128+131].
// MODE 1 (conv along H): block = (wgroup,b); iterates 4 cols w; window =
//   h in [-4, 131].
// Waves N-split: wave wv owns 32 output positions [wv*32,+32), all 64 co.
// a-frags loaded from global (L2-hot 72KB) inside the K-loop (VGPR-capped
// allocator rematerializes; proven pattern). x window chunk-XOR swizzled
// (slot s of row r holds chunk s^(r&7)) via pre-swizzled global source.
template<int MODE>
__global__ __launch_bounds__(256, 4) void conv3(const unsigned short* __restrict__ X,
                                                unsigned short* __restrict__ Y,
                                                const unsigned short* __restrict__ A2,
                                                const float* __restrict__ bias,
                                                const unsigned short* __restrict__ ZP) {
  __shared__ __align__(16) char lds[2 * 17408];
  char* xbuf0 = lds;
  char* xbuf1 = lds + 17408;

  const int t = threadIdx.x, b = blockIdx.y;
  const int lane = t & 63, wv = t >> 6;
  const int llo = lane & 15, lhi = lane >> 4;

  const int half   = MODE ? 0 : (blockIdx.x & 1);
  const int pgroup = MODE ? (int)blockIdx.x : (int)(blockIdx.x >> 1);
  const int sstart = MODE ? -4 : half * 128 - 4;     // staged-axis start
  constexpr int SLEN = MODE ? H_ : W_;

  // stage window for iterated position pos (h for MODE0, w for MODE1)
  auto stage = [&](char* xb, int pos) {
#pragma unroll
    for (int pass = 0; pass < 4; ++pass) {
      int q = pass * 256 + t;                  // chunk id 0..1023
      int r = q >> 3, slot = q & 7;
      int chunk = slot ^ (r & 7);
      int sp = sstart + r;
      const void* src;
      if ((unsigned)sp < (unsigned)SLEN) {
        size_t goff = MODE ? (((size_t)(b*H_ + sp)*W_ + pos)*C_ + chunk*8)
                           : (((size_t)(b*H_ + pos)*W_ + sp)*C_ + chunk*8);
        src = (const void*)(X + goff);
      } else {
        src = (const void*)(ZP + slot * 8);
      }
      gload_lds16(src, xb + pass * 4096 + wv * 1024);
    }
    if (wv == 0) {                             // tail rows 128..135
      int q = 1024 + lane;
      int r = q >> 3, slot = q & 7;
      int chunk = slot ^ (r & 7);
      int sp = sstart + r;
      const void* src;
      if ((unsigned)sp < (unsigned)SLEN) {
        size_t goff = MODE ? (((size_t)(b*H_ + sp)*W_ + pos)*C_ + chunk*8)
                           : (((size_t)(b*H_ + pos)*W_ + sp)*C_ + chunk*8);
        src = (const void*)(X + goff);
      } else {
        src = (const void*)(ZP + slot * 8);
      }
      gload_lds16(src, xb + 16384);
    }
  };

  float4 bv[4];
#pragma unroll
  for (int j = 0; j < 4; ++j) bv[j] = *(const float4*)(bias + j*16 + lhi*4);

  const int pos0 = MODE ? pgroup * 4 : 0;      // MODE0 iterates h, MODE1 iterates w
  const int h0   = MODE ? 0 : pgroup * 4;

  stage(xbuf0, MODE ? pos0 : h0);
  __syncthreads();

  const int nbase = wv * 32;

  for (int it = 0; it < 4; ++it) {
    char* cur = (it & 1) ? xbuf1 : xbuf0;
    char* nxt = (it & 1) ? xbuf0 : xbuf1;
    if (it + 1 < 4) stage(nxt, (MODE ? pos0 : h0) + it + 1);

    f32x4 acc[2][4];
#pragma unroll
    for (int i = 0; i < 2; ++i)
#pragma unroll
      for (int j = 0; j < 4; ++j) { f32x4 z = {0.f,0.f,0.f,0.f}; acc[i][j] = z; }

#pragma unroll
    for (int step = 0; step < 18; ++step) {
      short8_t a[4];
#pragma unroll
      for (int j = 0; j < 4; ++j)
        a[j] = *(const short8_t*)(A2 + (size_t)((step*4 + lhi)*64 + j*16 + llo) * 8);
      const int kk = step >> 1;
      const int cg = (step & 1) * 4 + lhi;
      short8_t bf[2];
#pragma unroll
      for (int i = 0; i < 2; ++i) {
        int r = nbase + i*16 + llo + kk;
        bf[i] = *(const short8_t*)(cur + r * 128 + ((cg ^ (r & 7)) << 4));
      }
#pragma unroll
      for (int i = 0; i < 2; ++i)
#pragma unroll
        for (int j = 0; j < 4; ++j)
          acc[i][j] = __builtin_amdgcn_mfma_f32_16x16x32_bf16(a[j], bf[i], acc[i][j], 0, 0, 0);
    }

    // epilogue: +bias, pack 4 consecutive co (8B stores)
#pragma unroll
    for (int j = 0; j < 4; ++j) {
      const int cb = j * 16 + lhi * 4;
#pragma unroll
      for (int i = 0; i < 2; ++i) {
        const int p = nbase + i * 16 + llo;
        size_t off;
        if (MODE == 0) { int h = h0 + it; int w = half * 128 + p;
          off = ((size_t)(b*H_ + h)*W_ + w)*C_ + cb; }
        else { int w = pos0 + it;
          off = ((size_t)(b*H_ + p)*W_ + w)*C_ + cb; }
        float v0 = acc[i][j][0] + bv[j].x;
        float v1 = acc[i][j][1] + bv[j].y;
        float v2 = acc[i][j][2] + bv[j].z;
        float v3 = acc[i][j][3] + bv[j].w;
        unsigned lo, hi;
        asm("v_cvt_pk_bf16_f32 %0, %1, %2" : "=v"(lo) : "v"(v0), "v"(v1));
        asm("v_cvt_pk_bf16_f32 %0, %1, %2" : "=v"(hi) : "v"(v2), "v"(v3));
        uint2 ov; ov.x = lo; ov.y = hi;
        *(uint2*)(Y + off) = ov;
      }
    }
    __syncthreads();
  }
}

// Scan along H, in-place, 2 ci (uint) per thread, depth-2 prefetch.
template<int REV>
__global__ __launch_bounds__(128) void scanH(unsigned short* __restrict__ buf,
                                             const unsigned short* __restrict__ prev) {
  int idx = blockIdx.x * 128 + threadIdx.x;      // B*W*32
  int cp = idx & 31, w = (idx >> 5) & 255, b = idx >> 13;
  const ptrdiff_t dh = (REV ? -1 : 1) * (ptrdiff_t)(W_ * C_);
  size_t off = ((size_t)(b * H_ + (REV ? H_ - 1 : 0)) * W_ + w) * C_ + cp * 2;
  unsigned pv = *(const unsigned*)(prev + off);
  *(unsigned*)(buf + off) = pv;
  float y0 = bf2f((unsigned short)pv), y1 = bf2f((unsigned short)(pv >> 16));
  unsigned c1 = *(const unsigned*)(buf + off + dh);
  unsigned c2 = *(const unsigned*)(buf + off + 2 * dh);
  for (int s = 1; s < H_; ++s) {
    off += dh;
    unsigned nx = (s + 2 < H_) ? *(const unsigned*)(buf + off + 2 * dh) : 0u;
    y0 = fmaxf(bf2f((unsigned short)c1) + y0, 0.f);
    y1 = fmaxf(bf2f((unsigned short)(c1 >> 16)) + y1, 0.f);
    *(unsigned*)(buf + off) = (unsigned)f2bf(y0) | ((unsigned)f2bf(y1) << 16);
    c1 = c2; c2 = nx;
  }
}

// Scan along W, in-place bf16, 4 ci (uint2, 8B) per thread, depth-8 prefetch.
template<int REV>
__global__ __launch_bounds__(128) void scanW2(unsigned short* __restrict__ buf,
                                              const unsigned short* __restrict__ prev) {
  int idx = blockIdx.x * 128 + threadIdx.x;      // B*H*16
  int cq = idx & 15, h = (idx >> 4) & 127, b = idx >> 11;
  const ptrdiff_t dw = (REV ? -1 : 1) * (ptrdiff_t)C_;
  size_t off = ((size_t)(b * H_ + h) * W_ + (REV ? W_ - 1 : 0)) * C_ + cq * 4;
  uint2 pv = *(const uint2*)(prev + off);
  *(uint2*)(buf + off) = pv;
  float y0 = bf2f((unsigned short)pv.x), y1 = bf2f((unsigned short)(pv.x >> 16));
  float y2 = bf2f((unsigned short)pv.y), y3 = bf2f((unsigned short)(pv.y >> 16));
  uint2 c[8];
#pragma unroll
  for (int j = 0; j < 8; ++j) c[j] = *(const uint2*)(buf + off + (ptrdiff_t)(j + 1) * dw);
  for (int base = 1; base < W_; base += 8) {
#pragma unroll
    for (int j = 0; j < 8; ++j) {
      int s = base + j;
      if (s < W_) {
        off += dw;
        y0 = fmaxf(bf2f((unsigned short)c[j].x) + y0, 0.f);
        y1 = fmaxf(bf2f((unsigned short)(c[j].x >> 16)) + y1, 0.f);
        y2 = fmaxf(bf2f((unsigned short)c[j].y) + y2, 0.f);
        y3 = fmaxf(bf2f((unsigned short)(c[j].y >> 16)) + y3, 0.f);
        uint2 ov;
        ov.x = (unsigned)f2bf(y0) | ((unsigned)f2bf(y1) << 16);
        ov.y = (unsigned)f2bf(y2) | ((unsigned)f2bf(y3) << 16);
        *(uint2*)(buf + off) = ov;
        if (s + 8 < W_) c[j] = *(const uint2*)(buf + off + 8 * dw);
      }
    }
  }
}

extern "C" void kernel_launch(void* const* d_in, const int* in_sizes, int n_in,
                              void* d_out, int out_size, void* d_ws, size_t ws_size,
                              hipStream_t stream) {
  const float* x    = (const float*)d_in[0];
  const float* w_ud = (const float*)d_in[1];
  const float* b_ud = (const float*)d_in[2];
  const float* w_du = (const float*)d_in[3];
  const float* b_du = (const float*)d_in[4];
  const float* w_lr = (const float*)d_in[5];
  const float* b_lr = (const float*)d_in[6];
  const float* w_rl = (const float*)d_in[7];
  const float* b_rl = (const float*)d_in[8];

  // ws: A[0,64M) Bb[64M,128M) Cc[128M,192M) A2 @192M, zeropage @192M+1M
  unsigned short* A  = (unsigned short*)d_ws;
  unsigned short* Bb = (unsigned short*)((char*)d_ws + 67108864);
  unsigned short* Cc = (unsigned short*)((char*)d_ws + 134217728);
  unsigned short* A2 = (unsigned short*)((char*)d_ws + 201326592);
  unsigned short* ZP = (unsigned short*)((char*)d_ws + 202375168);
  unsigned short* A2_ud = A2 + 0 * (C_ * KDIM_);
  unsigned short* A2_du = A2 + 1 * (C_ * KDIM_);
  unsigned short* A2_lr = A2 + 2 * (C_ * KDIM_);
  unsigned short* A2_rl = A2 + 3 * (C_ * KDIM_);

  hipMemsetAsync(ZP, 0, 1024, stream);

  dim3 pg((C_ * KDIM_ + 255) / 256, 4);
  prep_w_all<<<pg, 256, 0, stream>>>(w_ud, w_du, w_lr, w_rl, A2);

  transpose_in<<<dim3(4, H_, B_), 256, 0, stream>>>(x, A);

  // sweep 1: conv along W, scan along H (fwd)
  conv3<0><<<dim3(64, B_), 256, 0, stream>>>(A, Bb, A2_ud, b_ud, ZP);
  scanH<0><<<1024, 128, 0, stream>>>(Bb, A);

  // sweep 2: conv along W, scan along H (rev)
  conv3<0><<<dim3(64, B_), 256, 0, stream>>>(Bb, Cc, A2_du, b_du, ZP);
  scanH<1><<<1024, 128, 0, stream>>>(Cc, Bb);

  // sweep 3: conv along H, scan along W (fwd)
  conv3<1><<<dim3(64, B_), 256, 0, stream>>>(Cc, A, A2_lr, b_lr, ZP);
  scanW2<0><<<256, 128, 0, stream>>>(A, Cc);

  // sweep 4: conv along H, scan along W (rev)
  conv3<1><<<dim3(64, B_), 256, 0, stream>>>(A, Bb, A2_rl, b_rl, ZP);
  scanW2<1><<<256, 128, 0, stream>>>(Bb, A);

  transpose_out<<<dim3(4, H_, B_), 256, 0, stream>>>(Bb, (float*)d_out);
}

// Round 8
// 974.931 us; speedup vs baseline: 1.6235x; 1.6235x over previous
//
#include <hip/hip_runtime.h>

#define B_ 16
#define C_ 64
#define H_ 128
#define W_ 256
#define K_ 9
#define KDIM_ (K_*C_)            // 576

typedef __attribute__((ext_vector_type(8))) short short8_t;
typedef __attribute__((ext_vector_type(4))) float f32x4;

static __device__ __forceinline__ float bf2f(unsigned short u) {
  union { unsigned int i; float f; } v; v.i = ((unsigned int)u) << 16; return v.f;
}
static __device__ __forceinline__ unsigned short f2bf(float f) {
  union { float f; unsigned int i; } v; v.f = f;
  unsigned int r = v.i + 0x7FFF + ((v.i >> 16) & 1);   // RNE
  return (unsigned short)(r >> 16);
}

// async global->LDS, 16B per lane; lds base wave-uniform, lanes fill +lane*16
static __device__ __forceinline__ void gload_lds16(const void* g, void* l) {
  __builtin_amdgcn_global_load_lds(
      (const __attribute__((address_space(1))) unsigned int*)g,
      (__attribute__((address_space(3))) unsigned int*)l, 16, 0, 0);
}

// All 4 weight tensors [co][ci][kk] fp32 -> A2 chunk layout (16B chunk = 8
// consecutive k for one co): A2[(c*64+co)*8 + (k&7)], c = k>>3, k = kk*64+ci.
__global__ __launch_bounds__(256) void prep_w_all(const float* __restrict__ w0,
                                                  const float* __restrict__ w1,
                                                  const float* __restrict__ w2,
                                                  const float* __restrict__ w3,
                                                  unsigned short* __restrict__ A2) {
  int idx = blockIdx.x * 256 + threadIdx.x;
  if (idx >= C_ * KDIM_) return;
  int which = blockIdx.y;
  const float* w = (which == 0) ? w0 : (which == 1) ? w1 : (which == 2) ? w2 : w3;
  unsigned short* out = A2 + (size_t)which * (C_ * KDIM_);
  int co = idx / KDIM_, k = idx % KDIM_;
  int ci = k & 63, kk = k >> 6;
  out[((size_t)(k >> 3) * 64 + co) * 8 + (k & 7)] =
      f2bf(w[((size_t)co * C_ + ci) * K_ + kk]);
}

// fp32 NCHW -> bf16 ci-minor [b][h][w][ci]
__global__ __launch_bounds__(256) void transpose_in(const float* __restrict__ x,
                                                    unsigned short* __restrict__ Xt) {
  __shared__ float tile[64][65];
  const int w0 = blockIdx.x * 64, h = blockIdx.y, b = blockIdx.z;
  const int t = threadIdx.x;
#pragma unroll
  for (int rep = 0; rep < 16; ++rep) {
    int idx = rep * 256 + t;
    int ci = idx >> 6, wl = idx & 63;
    tile[ci][wl] = x[((size_t)(b * C_ + ci) * H_ + h) * W_ + w0 + wl];
  }
  __syncthreads();
#pragma unroll
  for (int rep = 0; rep < 8; ++rep) {
    int idx = rep * 256 + t;
    int wl = idx >> 5, cp = idx & 31;
    unsigned v = (unsigned)f2bf(tile[cp*2][wl]) | ((unsigned)f2bf(tile[cp*2+1][wl]) << 16);
    *(unsigned*)(Xt + ((size_t)(b * H_ + h) * W_ + w0 + wl) * C_ + cp * 2) = v;
  }
}

// [b][w][h][ci] bf16 -> fp32 NCHW (final output, after the layout flip)
__global__ __launch_bounds__(256) void transpose_out_wh(const unsigned short* __restrict__ F,
                                                        float* __restrict__ out) {
  __shared__ float tile[64][65];   // [wl][ci]
  const int w0 = blockIdx.x * 64, h = blockIdx.y, b = blockIdx.z;
  const int t = threadIdx.x;
#pragma unroll
  for (int rep = 0; rep < 4; ++rep) {
    int idx = rep * 256 + t;
    int cp = idx & 15, wl = idx >> 4;
    uint2 v = *(const uint2*)(F + ((size_t)(b * W_ + w0 + wl) * H_ + h) * C_ + cp * 4);
    tile[wl][cp*4+0] = bf2f((unsigned short)v.x);
    tile[wl][cp*4+1] = bf2f((unsigned short)(v.x >> 16));
    tile[wl][cp*4+2] = bf2f((unsigned short)v.y);
    tile[wl][cp*4+3] = bf2f((unsigned short)(v.y >> 16));
  }
  __syncthreads();
#pragma unroll
  for (int rep = 0; rep < 16; ++rep) {
    int idx = rep * 256 + t;
    int ci = idx >> 6, wl = idx & 63;
    out[((size_t)(b * C_ + ci) * H_ + h) * W_ + w0 + wl] = tile[wl][ci];
  }
}

// ===== conv4: barrier-free MFMA conv on layout [b][P][Q][ci], conv along Q =====
// 512 thr (8 waves), grid 256 (1 block/CU). A (72KB) staged once to LDS; then
// each wave independently does 4 units (rowId, seg): M=64 co x N=64 positions,
// K=576. B-fragments read straight from global (L2-resident row windows).
// Per K-step: 4 ds_read_b128 (A) + 4 global 16B loads (X) + 16 MFMA. No
// barriers in steady state -> 2 waves/SIMD cover latency.
template<int PLEN, int QLEN, int SEGS>
__global__ __launch_bounds__(512, 1) void conv4(const unsigned short* __restrict__ X,
                                                unsigned short* __restrict__ Y,
                                                const unsigned short* __restrict__ A2,
                                                const float* __restrict__ bias,
                                                const unsigned short* __restrict__ ZP) {
  __shared__ __align__(16) char Alds[73728];
  const int t = threadIdx.x;
  const int lane = t & 63, wv = t >> 6;
  const int llo = lane & 15, lhi = lane >> 4;

  // ---- stage A: 72 x 1KB chunks, linear ----
#pragma unroll
  for (int m = 0; m < 9; ++m) {
    int mm = m * 8 + wv;
    gload_lds16(A2 + (size_t)mm * 512 + lane * 8, Alds + mm * 1024);
  }
  __syncthreads();   // compiler drains vmcnt before barrier

  float4 bv[4];
#pragma unroll
  for (int j = 0; j < 4; ++j) bv[j] = *(const float4*)(bias + j * 16 + lhi * 4);

  const char* Ab = Alds + lhi * 1024 + llo * 16;
  const unsigned short* zp = ZP + lhi * 8;
  const int gw = blockIdx.x * 8 + wv;          // 0..2047

#pragma unroll 1
  for (int k = 0; k < 4; ++k) {
    const int u = gw * 4 + k;                  // 0..8191
    const int seg = u & (SEGS - 1);
    const int rowId = u / SEGS;                // b*PLEN + row
    const size_t rowbase = (size_t)rowId * (QLEN * 64);

    const int wb0 = seg * 64 + llo - 4;        // i=0 position base (can be <0)
    const int wb3 = wb0 + 48;                  // i=3 position base (can exceed)
    const unsigned short* g0 = X + rowbase + (ptrdiff_t)wb0 * 64 + lhi * 8;
    const unsigned short* g1 = g0 + 16 * 64;
    const unsigned short* g2 = g0 + 32 * 64;
    const unsigned short* g3 = g0 + 48 * 64;

    f32x4 acc[4][4];
#pragma unroll
    for (int i = 0; i < 4; ++i)
#pragma unroll
      for (int j = 0; j < 4; ++j) { f32x4 z = {0.f,0.f,0.f,0.f}; acc[i][j] = z; }

#pragma unroll
    for (int step = 0; step < 18; ++step) {
      const int kk = step >> 1;
      const int so = kk * 64 + (step & 1) * 32;     // shorts
      short8_t a[4];
#pragma unroll
      for (int j = 0; j < 4; ++j)
        a[j] = *(const short8_t*)(Ab + step * 4096 + j * 256);
      short8_t f0, f1, f2, f3;
      { const unsigned short* p = ((unsigned)(wb0 + kk) < (unsigned)QLEN) ? (g0 + so) : zp;
        f0 = *(const short8_t*)p; }
      f1 = *(const short8_t*)(g1 + so);
      f2 = *(const short8_t*)(g2 + so);
      { const unsigned short* p = ((unsigned)(wb3 + kk) < (unsigned)QLEN) ? (g3 + so) : zp;
        f3 = *(const short8_t*)p; }
#pragma unroll
      for (int j = 0; j < 4; ++j) acc[0][j] = __builtin_amdgcn_mfma_f32_16x16x32_bf16(a[j], f0, acc[0][j], 0, 0, 0);
#pragma unroll
      for (int j = 0; j < 4; ++j) acc[1][j] = __builtin_amdgcn_mfma_f32_16x16x32_bf16(a[j], f1, acc[1][j], 0, 0, 0);
#pragma unroll
      for (int j = 0; j < 4; ++j) acc[2][j] = __builtin_amdgcn_mfma_f32_16x16x32_bf16(a[j], f2, acc[2][j], 0, 0, 0);
#pragma unroll
      for (int j = 0; j < 4; ++j) acc[3][j] = __builtin_amdgcn_mfma_f32_16x16x32_bf16(a[j], f3, acc[3][j], 0, 0, 0);
    }

    // epilogue: +bias, pack 4 consecutive co, 8B stores
#pragma unroll
    for (int j = 0; j < 4; ++j) {
#pragma unroll
      for (int i = 0; i < 4; ++i) {
        const int q = seg * 64 + i * 16 + llo;
        float v0 = acc[i][j][0] + bv[j].x;
        float v1 = acc[i][j][1] + bv[j].y;
        float v2 = acc[i][j][2] + bv[j].z;
        float v3 = acc[i][j][3] + bv[j].w;
        unsigned lo, hi;
        asm("v_cvt_pk_bf16_f32 %0, %1, %2" : "=v"(lo) : "v"(v0), "v"(v1));
        asm("v_cvt_pk_bf16_f32 %0, %1, %2" : "=v"(hi) : "v"(v2), "v"(v3));
        uint2 ov; ov.x = lo; ov.y = hi;
        *(uint2*)(Y + rowbase + (size_t)q * 64 + j * 16 + lhi * 4) = ov;
      }
    }
  }
}

// ===== scan along the OUTER spatial dim P of layout [b][P][Q][ci] =====
// TRANS=1: write result transposed to [b][Q][P][ci] (outT) instead of in-place.
template<int PLEN, int QLEN, int REV, int TRANS>
__global__ __launch_bounds__(128) void scan_o(unsigned short* __restrict__ conv,
                                              const unsigned short* __restrict__ prev,
                                              unsigned short* __restrict__ outT) {
  int idx = blockIdx.x * 128 + threadIdx.x;     // B * QLEN * 32
  int cp = idx & 31;
  int q  = (idx >> 5) & (QLEN - 1);
  int b  = idx / (QLEN * 32);
  const ptrdiff_t dp = (REV ? -1 : 1) * (ptrdiff_t)(QLEN * 64);
  const int p0 = REV ? PLEN - 1 : 0;
  size_t off = ((size_t)(b * PLEN + p0) * QLEN + q) * 64 + cp * 2;
  size_t offT = 0; ptrdiff_t dpT = 0;
  if (TRANS) {
    offT = ((size_t)(b * QLEN + q) * PLEN + p0) * 64 + cp * 2;
    dpT = (REV ? -1 : 1) * (ptrdiff_t)64;
  }
  unsigned pv = *(const unsigned*)(prev + off);
  if (TRANS) *(unsigned*)(outT + offT) = pv; else *(unsigned*)(conv + off) = pv;
  float y0 = bf2f((unsigned short)pv), y1 = bf2f((unsigned short)(pv >> 16));
  unsigned c1 = *(const unsigned*)(conv + off + dp);
  unsigned c2 = *(const unsigned*)(conv + off + 2 * dp);
  for (int s = 1; s < PLEN; ++s) {
    off += dp;
    if (TRANS) offT += dpT;
    unsigned nx = (s + 2 < PLEN) ? *(const unsigned*)(conv + off + 2 * dp) : 0u;
    y0 = fmaxf(bf2f((unsigned short)c1) + y0, 0.f);
    y1 = fmaxf(bf2f((unsigned short)(c1 >> 16)) + y1, 0.f);
    unsigned ov = (unsigned)f2bf(y0) | ((unsigned)f2bf(y1) << 16);
    if (TRANS) *(unsigned*)(outT + offT) = ov; else *(unsigned*)(conv + off) = ov;
    c1 = c2; c2 = nx;
  }
}

extern "C" void kernel_launch(void* const* d_in, const int* in_sizes, int n_in,
                              void* d_out, int out_size, void* d_ws, size_t ws_size,
                              hipStream_t stream) {
  const float* x    = (const float*)d_in[0];
  const float* w_ud = (const float*)d_in[1];
  const float* b_ud = (const float*)d_in[2];
  const float* w_du = (const float*)d_in[3];
  const float* b_du = (const float*)d_in[4];
  const float* w_lr = (const float*)d_in[5];
  const float* b_lr = (const float*)d_in[6];
  const float* w_rl = (const float*)d_in[7];
  const float* b_rl = (const float*)d_in[8];

  // ws: A[0,64M) Bb[64M,128M) Cc[128M,192M) A2 @192M, zeropage @192M+1M
  unsigned short* A  = (unsigned short*)d_ws;
  unsigned short* Bb = (unsigned short*)((char*)d_ws + 67108864);
  unsigned short* Cc = (unsigned short*)((char*)d_ws + 134217728);
  unsigned short* A2 = (unsigned short*)((char*)d_ws + 201326592);
  unsigned short* ZP = (unsigned short*)((char*)d_ws + 202375168);
  unsigned short* A2_ud = A2 + 0 * (C_ * KDIM_);
  unsigned short* A2_du = A2 + 1 * (C_ * KDIM_);
  unsigned short* A2_lr = A2 + 2 * (C_ * KDIM_);
  unsigned short* A2_rl = A2 + 3 * (C_ * KDIM_);

  hipMemsetAsync(ZP, 0, 1024, stream);

  dim3 pg((C_ * KDIM_ + 255) / 256, 4);
  prep_w_all<<<pg, 256, 0, stream>>>(w_ud, w_du, w_lr, w_rl, A2);

  transpose_in<<<dim3(4, H_, B_), 256, 0, stream>>>(x, A);

  // sweep 1 (ud): conv along W on [b][h][w][ci]; scan fwd along h
  conv4<H_, W_, 4><<<256, 512, 0, stream>>>(A, Bb, A2_ud, b_ud, ZP);
  scan_o<H_, W_, 0, 0><<<1024, 128, 0, stream>>>(Bb, A, nullptr);

  // sweep 2 (du): conv along W; scan rev along h, WRITE TRANSPOSED -> [b][w][h][ci]
  conv4<H_, W_, 4><<<256, 512, 0, stream>>>(Bb, Cc, A2_du, b_du, ZP);
  scan_o<H_, W_, 1, 1><<<1024, 128, 0, stream>>>(Cc, Bb, A);

  // sweep 3 (lr): conv along H (inner dim of flipped layout); scan fwd along w
  conv4<W_, H_, 2><<<256, 512, 0, stream>>>(A, Bb, A2_lr, b_lr, ZP);
  scan_o<W_, H_, 0, 0><<<512, 128, 0, stream>>>(Bb, A, nullptr);

  // sweep 4 (rl): conv along H; scan rev along w
  conv4<W_, H_, 2><<<256, 512, 0, stream>>>(Bb, Cc, A2_rl, b_rl, ZP);
  scan_o<W_, H_, 1, 0><<<512, 128, 0, stream>>>(Cc, Bb, nullptr);

  transpose_out_wh<<<dim3(4, H_, B_), 256, 0, stream>>>(Cc, (float*)d_out);
}

// Round 9
// 376.923 us; speedup vs baseline: 4.1994x; 2.5865x over previous
//
#include <hip/hip_runtime.h>

#define B_ 16
#define C_ 64
#define H_ 128
#define W_ 256
#define K_ 9
#define KDIM_ (K_*C_)            // 576

typedef __attribute__((ext_vector_type(8))) short short8_t;
typedef __attribute__((ext_vector_type(4))) float f32x4;

static __device__ __forceinline__ float bf2f(unsigned short u) {
  union { unsigned int i; float f; } v; v.i = ((unsigned int)u) << 16; return v.f;
}
static __device__ __forceinline__ unsigned short f2bf(float f) {
  union { float f; unsigned int i; } v; v.f = f;
  unsigned int r = v.i + 0x7FFF + ((v.i >> 16) & 1);   // RNE
  return (unsigned short)(r >> 16);
}

// async global->LDS, 16B per lane; lds base wave-uniform, lanes fill +lane*16
static __device__ __forceinline__ void gload_lds16(const void* g, void* l) {
  __builtin_amdgcn_global_load_lds(
      (const __attribute__((address_space(1))) unsigned int*)g,
      (__attribute__((address_space(3))) unsigned int*)l, 16, 0, 0);
}

// Weights [co][ci][kk] fp32 -> A3 half-split chunk layout:
//   half = co>>5 (stride 18432 shorts = 36KB)
//   within half: chunk index = (k>>3)*32 + (co&31), 8 shorts of consecutive k
//   where k = kk*64 + ci.
__global__ __launch_bounds__(256) void prep_w_all(const float* __restrict__ w0,
                                                  const float* __restrict__ w1,
                                                  const float* __restrict__ w2,
                                                  const float* __restrict__ w3,
                                                  unsigned short* __restrict__ A3) {
  int idx = blockIdx.x * 256 + threadIdx.x;
  if (idx >= C_ * KDIM_) return;
  int which = blockIdx.y;
  const float* w = (which == 0) ? w0 : (which == 1) ? w1 : (which == 2) ? w2 : w3;
  unsigned short* out = A3 + (size_t)which * (C_ * KDIM_);
  int co = idx / KDIM_, k = idx % KDIM_;
  int ci = k & 63, kk = k >> 6;
  size_t off = (size_t)(co >> 5) * 18432 + ((size_t)(k >> 3) * 32 + (co & 31)) * 8 + (k & 7);
  out[off] = f2bf(w[((size_t)co * C_ + ci) * K_ + kk]);
}

// fp32 NCHW -> bf16 ci-minor [b][h][w][ci]
__global__ __launch_bounds__(256) void transpose_in(const float* __restrict__ x,
                                                    unsigned short* __restrict__ Xt) {
  __shared__ float tile[64][65];
  const int w0 = blockIdx.x * 64, h = blockIdx.y, b = blockIdx.z;
  const int t = threadIdx.x;
#pragma unroll
  for (int rep = 0; rep < 16; ++rep) {
    int idx = rep * 256 + t;
    int ci = idx >> 6, wl = idx & 63;
    tile[ci][wl] = x[((size_t)(b * C_ + ci) * H_ + h) * W_ + w0 + wl];
  }
  __syncthreads();
#pragma unroll
  for (int rep = 0; rep < 8; ++rep) {
    int idx = rep * 256 + t;
    int wl = idx >> 5, cp = idx & 31;
    unsigned v = (unsigned)f2bf(tile[cp*2][wl]) | ((unsigned)f2bf(tile[cp*2+1][wl]) << 16);
    *(unsigned*)(Xt + ((size_t)(b * H_ + h) * W_ + w0 + wl) * C_ + cp * 2) = v;
  }
}

// [b][w][h][ci] bf16 -> fp32 NCHW (final output, after the layout flip)
__global__ __launch_bounds__(256) void transpose_out_wh(const unsigned short* __restrict__ F,
                                                        float* __restrict__ out) {
  __shared__ float tile[64][65];   // [wl][ci]
  const int w0 = blockIdx.x * 64, h = blockIdx.y, b = blockIdx.z;
  const int t = threadIdx.x;
#pragma unroll
  for (int rep = 0; rep < 4; ++rep) {
    int idx = rep * 256 + t;
    int cp = idx & 15, wl = idx >> 4;
    uint2 v = *(const uint2*)(F + ((size_t)(b * W_ + w0 + wl) * H_ + h) * C_ + cp * 4);
    tile[wl][cp*4+0] = bf2f((unsigned short)v.x);
    tile[wl][cp*4+1] = bf2f((unsigned short)(v.x >> 16));
    tile[wl][cp*4+2] = bf2f((unsigned short)v.y);
    tile[wl][cp*4+3] = bf2f((unsigned short)(v.y >> 16));
  }
  __syncthreads();
#pragma unroll
  for (int rep = 0; rep < 16; ++rep) {
    int idx = rep * 256 + t;
    int ci = idx >> 6, wl = idx & 63;
    out[((size_t)(b * C_ + ci) * H_ + h) * W_ + w0 + wl] = tile[wl][ci];
  }
}

// ===== conv5: persistent co-split MFMA conv on [b][P][Q][ci], conv along Q =====
// Grid 512 = {co-half = bid>>8} x {slot pb = bid&255}; 256 thr (4 waves);
// 2 blocks/CU (LDS 70KB). A-half (36KB) staged to LDS once per block.
// Per block: 16 tiles (128 Q-positions each), X window (136 rows x 128B)
// double-buffered via swizzled global_load_lds (slot s of row r holds chunk
// s^(r&7), pre-swizzled source). Wave wv owns positions [wv*32,+32).
// Per wave per K-step: 2 A ds_reads + 2 X ds_reads + 4 MFMA.
template<int QLEN>
__global__ __launch_bounds__(256, 2) void conv5(const unsigned short* __restrict__ X,
                                                unsigned short* __restrict__ Y,
                                                const unsigned short* __restrict__ A3,
                                                const float* __restrict__ bias,
                                                const unsigned short* __restrict__ ZP) {
  __shared__ __align__(16) char lds[36864 + 2 * 17408];
  char* Alds  = lds;
  char* xbuf0 = lds + 36864;
  char* xbuf1 = lds + 36864 + 17408;

  const int t = threadIdx.x;
  const int lane = t & 63, wv = t >> 6;
  const int llo = lane & 15, lhi = lane >> 4;
  const int coh = blockIdx.x >> 8;       // pairs (pb,0)/(pb,1) land on same XCD
  const int pb  = blockIdx.x & 255;
  constexpr int SEGS = QLEN / 128;

  // ---- A-half -> LDS (36 groups of 1KB; 9 per wave) ----
  const unsigned short* Ah = A3 + coh * 18432;
#pragma unroll
  for (int i = 0; i < 9; ++i) {
    int m = i * 4 + wv;
    gload_lds16(Ah + (size_t)(m * 64 + lane) * 8, Alds + m * 1024);
  }

  auto stageX = [&](char* dst, int u) {
    const int qseg  = u & (SEGS - 1);
    const int rowId = u / SEGS;
    const size_t rowbase = (size_t)rowId * (QLEN * 64);
    const int q0 = qseg * 128 - 4;
#pragma unroll
    for (int i = 0; i < 4; ++i) {
      int g = wv + i * 4;                    // groups 0..15
      int r = g * 8 + (lane >> 3), slot = lane & 7;
      int chunk = slot ^ (r & 7);
      int sp = q0 + r;
      const void* src = ((unsigned)sp < (unsigned)QLEN)
          ? (const void*)(X + rowbase + (size_t)sp * 64 + chunk * 8)
          : (const void*)(ZP + slot * 8);
      gload_lds16(src, dst + g * 1024);
    }
    if (wv == 0) {                            // group 16 (rows 128..135)
      int r = 128 + (lane >> 3), slot = lane & 7;
      int chunk = slot ^ (r & 7);
      int sp = q0 + r;
      const void* src = ((unsigned)sp < (unsigned)QLEN)
          ? (const void*)(X + rowbase + (size_t)sp * 64 + chunk * 8)
          : (const void*)(ZP + slot * 8);
      gload_lds16(src, dst + 16 * 1024);
    }
  };

  float4 bv[2];
#pragma unroll
  for (int j = 0; j < 2; ++j) bv[j] = *(const float4*)(bias + coh * 32 + j * 16 + lhi * 4);

  stageX(xbuf0, pb * 16);
  __syncthreads();   // drains A + first X stage

  for (int tt = 0; tt < 16; ++tt) {
    const int u = pb * 16 + tt;
    char* cur = (tt & 1) ? xbuf1 : xbuf0;
    char* nxt = (tt & 1) ? xbuf0 : xbuf1;
    if (tt < 15) stageX(nxt, u + 1);          // issue BEFORE compute

    const int qseg  = u & (SEGS - 1);
    const int rowId = u / SEGS;
    const size_t rowbase = (size_t)rowId * (QLEN * 64);

    f32x4 acc[2][2];
#pragma unroll
    for (int i = 0; i < 2; ++i)
#pragma unroll
      for (int j = 0; j < 2; ++j) { f32x4 z = {0.f,0.f,0.f,0.f}; acc[i][j] = z; }

#pragma unroll
    for (int step = 0; step < 18; ++step) {
      const int kk = step >> 1;
      const int cg = (step & 1) * 4 + lhi;
      short8_t a0 = *(const short8_t*)(Alds + step * 2048 + lhi * 512 + llo * 16);
      short8_t a1 = *(const short8_t*)(Alds + step * 2048 + lhi * 512 + 256 + llo * 16);
      short8_t f0, f1;
      { int r = wv * 32 + llo + kk;
        f0 = *(const short8_t*)(cur + r * 128 + ((cg ^ (r & 7)) << 4)); }
      { int r = wv * 32 + 16 + llo + kk;
        f1 = *(const short8_t*)(cur + r * 128 + ((cg ^ (r & 7)) << 4)); }
      acc[0][0] = __builtin_amdgcn_mfma_f32_16x16x32_bf16(a0, f0, acc[0][0], 0, 0, 0);
      acc[0][1] = __builtin_amdgcn_mfma_f32_16x16x32_bf16(a1, f0, acc[0][1], 0, 0, 0);
      acc[1][0] = __builtin_amdgcn_mfma_f32_16x16x32_bf16(a0, f1, acc[1][0], 0, 0, 0);
      acc[1][1] = __builtin_amdgcn_mfma_f32_16x16x32_bf16(a1, f1, acc[1][1], 0, 0, 0);
    }

    // epilogue: +bias, pack 4 co (8B stores into this half's 64B sub-row)
#pragma unroll
    for (int i = 0; i < 2; ++i)
#pragma unroll
      for (int j = 0; j < 2; ++j) {
        const int q = qseg * 128 + wv * 32 + i * 16 + llo;
        float v0 = acc[i][j][0] + bv[j].x;
        float v1 = acc[i][j][1] + bv[j].y;
        float v2 = acc[i][j][2] + bv[j].z;
        float v3 = acc[i][j][3] + bv[j].w;
        unsigned lo, hi;
        asm("v_cvt_pk_bf16_f32 %0, %1, %2" : "=v"(lo) : "v"(v0), "v"(v1));
        asm("v_cvt_pk_bf16_f32 %0, %1, %2" : "=v"(hi) : "v"(v2), "v"(v3));
        uint2 ov; ov.x = lo; ov.y = hi;
        *(uint2*)(Y + rowbase + (size_t)q * 64 + coh * 32 + j * 16 + lhi * 4) = ov;
      }
    __syncthreads();
  }
}

// ===== scan along the OUTER spatial dim P of layout [b][P][Q][ci] =====
// TRANS=1: write result transposed to [b][Q][P][ci] (outT) instead of in-place.
template<int PLEN, int QLEN, int REV, int TRANS>
__global__ __launch_bounds__(128) void scan_o(unsigned short* __restrict__ conv,
                                              const unsigned short* __restrict__ prev,
                                              unsigned short* __restrict__ outT) {
  int idx = blockIdx.x * 128 + threadIdx.x;     // B * QLEN * 32
  int cp = idx & 31;
  int q  = (idx >> 5) & (QLEN - 1);
  int b  = idx / (QLEN * 32);
  const ptrdiff_t dp = (REV ? -1 : 1) * (ptrdiff_t)(QLEN * 64);
  const int p0 = REV ? PLEN - 1 : 0;
  size_t off = ((size_t)(b * PLEN + p0) * QLEN + q) * 64 + cp * 2;
  size_t offT = 0; ptrdiff_t dpT = 0;
  if (TRANS) {
    offT = ((size_t)(b * QLEN + q) * PLEN + p0) * 64 + cp * 2;
    dpT = (REV ? -1 : 1) * (ptrdiff_t)64;
  }
  unsigned pv = *(const unsigned*)(prev + off);
  if (TRANS) *(unsigned*)(outT + offT) = pv; else *(unsigned*)(conv + off) = pv;
  float y0 = bf2f((unsigned short)pv), y1 = bf2f((unsigned short)(pv >> 16));
  unsigned c1 = *(const unsigned*)(conv + off + dp);
  unsigned c2 = *(const unsigned*)(conv + off + 2 * dp);
  for (int s = 1; s < PLEN; ++s) {
    off += dp;
    if (TRANS) offT += dpT;
    unsigned nx = (s + 2 < PLEN) ? *(const unsigned*)(conv + off + 2 * dp) : 0u;
    y0 = fmaxf(bf2f((unsigned short)c1) + y0, 0.f);
    y1 = fmaxf(bf2f((unsigned short)(c1 >> 16)) + y1, 0.f);
    unsigned ov = (unsigned)f2bf(y0) | ((unsigned)f2bf(y1) << 16);
    if (TRANS) *(unsigned*)(outT + offT) = ov; else *(unsigned*)(conv + off) = ov;
    c1 = c2; c2 = nx;
  }
}

extern "C" void kernel_launch(void* const* d_in, const int* in_sizes, int n_in,
                              void* d_out, int out_size, void* d_ws, size_t ws_size,
                              hipStream_t stream) {
  const float* x    = (const float*)d_in[0];
  const float* w_ud = (const float*)d_in[1];
  const float* b_ud = (const float*)d_in[2];
  const float* w_du = (const float*)d_in[3];
  const float* b_du = (const float*)d_in[4];
  const float* w_lr = (const float*)d_in[5];
  const float* b_lr = (const float*)d_in[6];
  const float* w_rl = (const float*)d_in[7];
  const float* b_rl = (const float*)d_in[8];

  // ws: A[0,64M) Bb[64M,128M) Cc[128M,192M) A3 @192M, zeropage @192M+1M
  unsigned short* A  = (unsigned short*)d_ws;
  unsigned short* Bb = (unsigned short*)((char*)d_ws + 67108864);
  unsigned short* Cc = (unsigned short*)((char*)d_ws + 134217728);
  unsigned short* A3 = (unsigned short*)((char*)d_ws + 201326592);
  unsigned short* ZP = (unsigned short*)((char*)d_ws + 202375168);
  unsigned short* A3_ud = A3 + 0 * (C_ * KDIM_);
  unsigned short* A3_du = A3 + 1 * (C_ * KDIM_);
  unsigned short* A3_lr = A3 + 2 * (C_ * KDIM_);
  unsigned short* A3_rl = A3 + 3 * (C_ * KDIM_);

  hipMemsetAsync(ZP, 0, 1024, stream);

  dim3 pg((C_ * KDIM_ + 255) / 256, 4);
  prep_w_all<<<pg, 256, 0, stream>>>(w_ud, w_du, w_lr, w_rl, A3);

  transpose_in<<<dim3(4, H_, B_), 256, 0, stream>>>(x, A);

  // sweep 1 (ud): conv along W on [b][h][w][ci]; scan fwd along h
  conv5<W_><<<512, 256, 0, stream>>>(A, Bb, A3_ud, b_ud, ZP);
  scan_o<H_, W_, 0, 0><<<1024, 128, 0, stream>>>(Bb, A, nullptr);

  // sweep 2 (du): conv along W; scan rev along h, WRITE TRANSPOSED -> [b][w][h][ci]
  conv5<W_><<<512, 256, 0, stream>>>(Bb, Cc, A3_du, b_du, ZP);
  scan_o<H_, W_, 1, 1><<<1024, 128, 0, stream>>>(Cc, Bb, A);

  // sweep 3 (lr): conv along H (inner dim of flipped layout); scan fwd along w
  conv5<H_><<<512, 256, 0, stream>>>(A, Bb, A3_lr, b_lr, ZP);
  scan_o<W_, H_, 0, 0><<<512, 128, 0, stream>>>(Bb, A, nullptr);

  // sweep 4 (rl): conv along H; scan rev along w
  conv5<H_><<<512, 256, 0, stream>>>(Bb, Cc, A3_rl, b_rl, ZP);
  scan_o<W_, H_, 1, 0><<<512, 128, 0, stream>>>(Cc, Bb, nullptr);

  transpose_out_wh<<<dim3(4, H_, B_), 256, 0, stream>>>(Cc, (float*)d_out);
}

// Round 10
// 375.943 us; speedup vs baseline: 4.2103x; 1.0026x over previous
//
#include <hip/hip_runtime.h>

#define B_ 16
#define C_ 64
#define H_ 128
#define W_ 256
#define K_ 9
#define KDIM_ (K_*C_)            // 576

typedef __attribute__((ext_vector_type(8))) short short8_t;
typedef __attribute__((ext_vector_type(4))) float f32x4;

static __device__ __forceinline__ float bf2f(unsigned short u) {
  union { unsigned int i; float f; } v; v.i = ((unsigned int)u) << 16; return v.f;
}
static __device__ __forceinline__ unsigned short f2bf(float f) {
  union { float f; unsigned int i; } v; v.f = f;
  unsigned int r = v.i + 0x7FFF + ((v.i >> 16) & 1);   // RNE
  return (unsigned short)(r >> 16);
}

// async global->LDS, 16B per lane; lds base wave-uniform, lanes fill +lane*16
static __device__ __forceinline__ void gload_lds16(const void* g, void* l) {
  __builtin_amdgcn_global_load_lds(
      (const __attribute__((address_space(1))) unsigned int*)g,
      (__attribute__((address_space(3))) unsigned int*)l, 16, 0, 0);
}

// All 4 weight tensors [co][ci][kk] fp32 -> A2 chunk layout (16B chunk = 8
// consecutive k for one co): A2[((k>>3)*64+co)*8 + (k&7)], k = kk*64+ci.
__global__ __launch_bounds__(256) void prep_w_all(const float* __restrict__ w0,
                                                  const float* __restrict__ w1,
                                                  const float* __restrict__ w2,
                                                  const float* __restrict__ w3,
                                                  unsigned short* __restrict__ A2) {
  int idx = blockIdx.x * 256 + threadIdx.x;
  if (idx >= C_ * KDIM_) return;
  int which = blockIdx.y;
  const float* w = (which == 0) ? w0 : (which == 1) ? w1 : (which == 2) ? w2 : w3;
  unsigned short* out = A2 + (size_t)which * (C_ * KDIM_);
  int co = idx / KDIM_, k = idx % KDIM_;
  int ci = k & 63, kk = k >> 6;
  out[((size_t)(k >> 3) * 64 + co) * 8 + (k & 7)] =
      f2bf(w[((size_t)co * C_ + ci) * K_ + kk]);
}

// fp32 NCHW -> bf16 ci-minor [b][h][w][ci]
__global__ __launch_bounds__(256) void transpose_in(const float* __restrict__ x,
                                                    unsigned short* __restrict__ Xt) {
  __shared__ float tile[64][65];
  const int w0 = blockIdx.x * 64, h = blockIdx.y, b = blockIdx.z;
  const int t = threadIdx.x;
#pragma unroll
  for (int rep = 0; rep < 16; ++rep) {
    int idx = rep * 256 + t;
    int ci = idx >> 6, wl = idx & 63;
    tile[ci][wl] = x[((size_t)(b * C_ + ci) * H_ + h) * W_ + w0 + wl];
  }
  __syncthreads();
#pragma unroll
  for (int rep = 0; rep < 8; ++rep) {
    int idx = rep * 256 + t;
    int wl = idx >> 5, cp = idx & 31;
    unsigned v = (unsigned)f2bf(tile[cp*2][wl]) | ((unsigned)f2bf(tile[cp*2+1][wl]) << 16);
    *(unsigned*)(Xt + ((size_t)(b * H_ + h) * W_ + w0 + wl) * C_ + cp * 2) = v;
  }
}

// [b][w][h][ci] bf16 -> fp32 NCHW (final output, after the layout flip)
__global__ __launch_bounds__(256) void transpose_out_wh(const unsigned short* __restrict__ F,
                                                        float* __restrict__ out) {
  __shared__ float tile[64][65];   // [wl][ci]
  const int w0 = blockIdx.x * 64, h = blockIdx.y, b = blockIdx.z;
  const int t = threadIdx.x;
#pragma unroll
  for (int rep = 0; rep < 4; ++rep) {
    int idx = rep * 256 + t;
    int cp = idx & 15, wl = idx >> 4;
    uint2 v = *(const uint2*)(F + ((size_t)(b * W_ + w0 + wl) * H_ + h) * C_ + cp * 4);
    tile[wl][cp*4+0] = bf2f((unsigned short)v.x);
    tile[wl][cp*4+1] = bf2f((unsigned short)(v.x >> 16));
    tile[wl][cp*4+2] = bf2f((unsigned short)v.y);
    tile[wl][cp*4+3] = bf2f((unsigned short)(v.y >> 16));
  }
  __syncthreads();
#pragma unroll
  for (int rep = 0; rep < 16; ++rep) {
    int idx = rep * 256 + t;
    int ci = idx >> 6, wl = idx & 63;
    out[((size_t)(b * C_ + ci) * H_ + h) * W_ + w0 + wl] = tile[wl][ci];
  }
}

// ===== conv6: square-tile MFMA conv on [b][R][Q][ci], conv along Q =====
// Grid 256 (1 block/CU, LDS 143KB), 4 waves. Full A (72KB) in LDS; X staged
// as 256-position super-tiles, double-buffered (34KB each, swizzled: LDS slot
// s of row r holds chunk s^(r&7) via pre-swizzled global source).
// QLEN=256: super-tile = 1 row (264 LDS rows incl pads).
// QLEN=128: super-tile = 2 consecutive rows as 2 strips of 136 LDS rows.
// Wave wv owns 64 positions x all 64 co (4x4 MFMA tiles): per K-step
// 4 A ds_reads + 4 X ds_reads feed 16 MFMAs -> MFMA-bound, LDS no longer.
template<int QLEN>
__global__ __launch_bounds__(256, 1) void conv6(const unsigned short* __restrict__ X,
                                                unsigned short* __restrict__ Y,
                                                const unsigned short* __restrict__ A2,
                                                const float* __restrict__ bias,
                                                const unsigned short* __restrict__ ZP) {
  constexpr int SEGROWS = 256 / QLEN;            // 1 or 2 strips
  constexpr int NG      = (256 + 8 * SEGROWS) / 8; // 33 or 34 groups of 1KB
  __shared__ __align__(16) char lds[73728 + 2 * 34816];
  char* Alds  = lds;
  char* xbuf0 = lds + 73728;
  char* xbuf1 = lds + 73728 + 34816;

  const int t = threadIdx.x;
  const int lane = t & 63, wv = t >> 6;
  const int llo = lane & 15, lhi = lane >> 4;

  // ---- A -> LDS: 72 x 1KB groups, 18 per wave ----
#pragma unroll
  for (int i = 0; i < 18; ++i) {
    int m = wv + i * 4;
    gload_lds16(A2 + (size_t)m * 512 + lane * 8, Alds + m * 1024);
  }

  // stage super-tile u into dst
  auto stageX = [&](char* dst, int u) {
#pragma unroll
    for (int i = 0; i < 9; ++i) {
      int gl = wv + i * 4;
      if (gl < NG) {
        int strip = (SEGROWS == 2 && gl >= 17) ? 1 : 0;
        int gg = gl - strip * 17;
        int r = gg * 8 + (lane >> 3);            // row within strip
        int slot = lane & 7;
        int chunk = slot ^ (r & 7);
        int q = r - 4;
        int rowId = (SEGROWS == 1) ? u : u * 2 + strip;
        const void* src = ((unsigned)q < (unsigned)QLEN)
            ? (const void*)(X + (size_t)rowId * (QLEN * 64) + (size_t)q * 64 + chunk * 8)
            : (const void*)(ZP + slot * 8);
        gload_lds16(src, dst + strip * 17408 + gg * 1024);
      }
    }
  };

  float4 bv[4];
#pragma unroll
  for (int j = 0; j < 4; ++j) bv[j] = *(const float4*)(bias + j * 16 + lhi * 4);

  const int stripoff = (SEGROWS == 1) ? 0 : (wv >> 1) * 17408;
  const int posbase  = (SEGROWS == 1) ? wv * 64 : (wv & 1) * 64;

  const int u0 = blockIdx.x * 8;
  stageX(xbuf0, u0);
  __syncthreads();

  for (int tt = 0; tt < 8; ++tt) {
    const int u = u0 + tt;
    char* cur = (tt & 1) ? xbuf1 : xbuf0;
    char* nxt = (tt & 1) ? xbuf0 : xbuf1;
    if (tt < 7) stageX(nxt, u + 1);              // issue BEFORE compute

    const char* xb = cur + stripoff;
    f32x4 acc[4][4];
#pragma unroll
    for (int i = 0; i < 4; ++i)
#pragma unroll
      for (int j = 0; j < 4; ++j) { f32x4 z = {0.f,0.f,0.f,0.f}; acc[i][j] = z; }

#pragma unroll
    for (int step = 0; step < 18; ++step) {
      const int kk = step >> 1;
      const int cg = (step & 1) * 4 + lhi;
      short8_t a[4], f[4];
#pragma unroll
      for (int j = 0; j < 4; ++j)
        a[j] = *(const short8_t*)(Alds + step * 4096 + lhi * 1024 + j * 256 + llo * 16);
#pragma unroll
      for (int i = 0; i < 4; ++i) {
        int r = posbase + i * 16 + llo + kk;
        f[i] = *(const short8_t*)(xb + r * 128 + ((cg ^ (r & 7)) << 4));
      }
#pragma unroll
      for (int i = 0; i < 4; ++i)
#pragma unroll
        for (int j = 0; j < 4; ++j)
          acc[i][j] = __builtin_amdgcn_mfma_f32_16x16x32_bf16(a[j], f[i], acc[i][j], 0, 0, 0);
    }

    // epilogue: +bias, pack 4 consecutive co, 8B stores
    const int outRow = (SEGROWS == 1) ? u : u * 2 + (wv >> 1);
    const size_t rowbase = (size_t)outRow * (QLEN * 64);
#pragma unroll
    for (int j = 0; j < 4; ++j) {
#pragma unroll
      for (int i = 0; i < 4; ++i) {
        const int q = posbase + i * 16 + llo;
        float v0 = acc[i][j][0] + bv[j].x;
        float v1 = acc[i][j][1] + bv[j].y;
        float v2 = acc[i][j][2] + bv[j].z;
        float v3 = acc[i][j][3] + bv[j].w;
        unsigned lo, hi;
        asm("v_cvt_pk_bf16_f32 %0, %1, %2" : "=v"(lo) : "v"(v0), "v"(v1));
        asm("v_cvt_pk_bf16_f32 %0, %1, %2" : "=v"(hi) : "v"(v2), "v"(v3));
        uint2 ov; ov.x = lo; ov.y = hi;
        *(uint2*)(Y + rowbase + (size_t)q * 64 + j * 16 + lhi * 4) = ov;
      }
    }
    __syncthreads();
  }
}

// ===== scan along OUTER dim P of [b][P][Q][ci], 4 ci/thread, depth-8 =====
// TRANS=1: write result transposed to [b][Q][P][ci] (outT) instead of in-place.
template<int PLEN, int QLEN, int REV, int TRANS>
__global__ __launch_bounds__(128) void scan_o4(unsigned short* __restrict__ conv,
                                               const unsigned short* __restrict__ prev,
                                               unsigned short* __restrict__ outT) {
  int idx = blockIdx.x * 128 + threadIdx.x;     // B * QLEN * 16
  int cq = idx & 15;
  int q  = (idx >> 4) % QLEN;
  int b  = idx / (16 * QLEN);
  const ptrdiff_t dp = (REV ? -1 : 1) * (ptrdiff_t)(QLEN * 64);
  const int p0 = REV ? PLEN - 1 : 0;
  size_t off = ((size_t)(b * PLEN + p0) * QLEN + q) * 64 + cq * 4;
  size_t offT = 0; ptrdiff_t dpT = 0;
  if (TRANS) {
    offT = ((size_t)(b * QLEN + q) * PLEN + p0) * 64 + cq * 4;
    dpT = (REV ? -1 : 1) * (ptrdiff_t)64;
  }
  uint2 pv = *(const uint2*)(prev + off);
  if (TRANS) *(uint2*)(outT + offT) = pv; else *(uint2*)(conv + off) = pv;
  float y0 = bf2f((unsigned short)pv.x), y1 = bf2f((unsigned short)(pv.x >> 16));
  float y2 = bf2f((unsigned short)pv.y), y3 = bf2f((unsigned short)(pv.y >> 16));
  uint2 c[8];
#pragma unroll
  for (int j = 0; j < 8; ++j) c[j] = *(const uint2*)(conv + off + (ptrdiff_t)(j + 1) * dp);
  for (int base = 1; base < PLEN; base += 8) {
#pragma unroll
    for (int j = 0; j < 8; ++j) {
      int s = base + j;
      if (s < PLEN) {
        off += dp;
        if (TRANS) offT += dpT;
        y0 = fmaxf(bf2f((unsigned short)c[j].x) + y0, 0.f);
        y1 = fmaxf(bf2f((unsigned short)(c[j].x >> 16)) + y1, 0.f);
        y2 = fmaxf(bf2f((unsigned short)c[j].y) + y2, 0.f);
        y3 = fmaxf(bf2f((unsigned short)(c[j].y >> 16)) + y3, 0.f);
        uint2 ov;
        ov.x = (unsigned)f2bf(y0) | ((unsigned)f2bf(y1) << 16);
        ov.y = (unsigned)f2bf(y2) | ((unsigned)f2bf(y3) << 16);
        if (TRANS) *(uint2*)(outT + offT) = ov; else *(uint2*)(conv + off) = ov;
        if (s + 8 < PLEN) c[j] = *(const uint2*)(conv + off + 8 * dp);
      }
    }
  }
}

extern "C" void kernel_launch(void* const* d_in, const int* in_sizes, int n_in,
                              void* d_out, int out_size, void* d_ws, size_t ws_size,
                              hipStream_t stream) {
  const float* x    = (const float*)d_in[0];
  const float* w_ud = (const float*)d_in[1];
  const float* b_ud = (const float*)d_in[2];
  const float* w_du = (const float*)d_in[3];
  const float* b_du = (const float*)d_in[4];
  const float* w_lr = (const float*)d_in[5];
  const float* b_lr = (const float*)d_in[6];
  const float* w_rl = (const float*)d_in[7];
  const float* b_rl = (const float*)d_in[8];

  // ws: A[0,64M) Bb[64M,128M) Cc[128M,192M) A2 @192M, zeropage @192M+1M
  unsigned short* A  = (unsigned short*)d_ws;
  unsigned short* Bb = (unsigned short*)((char*)d_ws + 67108864);
  unsigned short* Cc = (unsigned short*)((char*)d_ws + 134217728);
  unsigned short* A2 = (unsigned short*)((char*)d_ws + 201326592);
  unsigned short* ZP = (unsigned short*)((char*)d_ws + 202375168);
  unsigned short* A2_ud = A2 + 0 * (C_ * KDIM_);
  unsigned short* A2_du = A2 + 1 * (C_ * KDIM_);
  unsigned short* A2_lr = A2 + 2 * (C_ * KDIM_);
  unsigned short* A2_rl = A2 + 3 * (C_ * KDIM_);

  hipMemsetAsync(ZP, 0, 1024, stream);

  dim3 pg((C_ * KDIM_ + 255) / 256, 4);
  prep_w_all<<<pg, 256, 0, stream>>>(w_ud, w_du, w_lr, w_rl, A2);

  transpose_in<<<dim3(4, H_, B_), 256, 0, stream>>>(x, A);

  // sweep 1 (ud): conv along W on [b][h][w][ci]; scan fwd along h
  conv6<W_><<<256, 256, 0, stream>>>(A, Bb, A2_ud, b_ud, ZP);
  scan_o4<H_, W_, 0, 0><<<512, 128, 0, stream>>>(Bb, A, nullptr);

  // sweep 2 (du): conv along W; scan rev along h, WRITE TRANSPOSED -> [b][w][h][ci]
  conv6<W_><<<256, 256, 0, stream>>>(Bb, Cc, A2_du, b_du, ZP);
  scan_o4<H_, W_, 1, 1><<<512, 128, 0, stream>>>(Cc, Bb, A);

  // sweep 3 (lr): conv along H (inner dim of flipped layout); scan fwd along w
  conv6<H_><<<256, 256, 0, stream>>>(A, Bb, A2_lr, b_lr, ZP);
  scan_o4<W_, H_, 0, 0><<<256, 128, 0, stream>>>(Bb, A, nullptr);

  // sweep 4 (rl): conv along H; scan rev along w
  conv6<H_><<<256, 256, 0, stream>>>(Bb, Cc, A2_rl, b_rl, ZP);
  scan_o4<W_, H_, 1, 0><<<256, 128, 0, stream>>>(Cc, Bb, nullptr);

  transpose_out_wh<<<dim3(4, H_, B_), 256, 0, stream>>>(Cc, (float*)d_out);
}